// Round 4
// baseline (355.075 us; speedup 1.0000x reference)
//
#include <hip/hip_runtime.h>

// Recall over [B=32, F=512, T=2048]:
//   p_adj[b,f,t] = predicted[b, f==0?1:f, t==0?1:t]
//   out = sum(p_adj * (gt!=0)) / count(gt!=0), or 0 if count==0.
//
// R13: single-kernel fusion via the LAST-BLOCK TICKET pattern (graph-safe,
// unlike R12's hipLaunchCooperativeKernel which silently no-op'd under
// graph capture -> absmax 0.5 = unwritten output). Each block writes its
// partial sum/count, release-fences (__threadfence = device scope, forces
// cross-XCD visibility), and takes a ticket via device-scope atomicAdd.
// The block drawing ticket NBLK-1 acquire-fences and reduces the 2048
// partials in the EXACT arithmetic order of the old recall_fin
// (bit-identical numerics). Ticket word is memset to 0 each launch
// (stream-ordered, capturable) and re-zeroed by the winner.
// Streaming loop verbatim from R11 (nt loads, 4-deep batching, descending
// block->data mapping, fused edge correction; 2048 blocks x 256 thr,
// 8 blocks/CU, single resident round).

constexpr int B_ = 32;
constexpr int F_ = 512;
constexpr int T_ = 2048;
constexpr long long NTOT = (long long)B_ * F_ * T_;   // 2^25
constexpr int NQ      = (int)(NTOT >> 2);             // 8,388,608 quads
constexpr int BLK     = 256;
constexpr int NBLK    = 2048;                         // 8 blocks/CU, 1 round
constexpr int QPB     = NQ / NBLK;                    // 4096 quads per block
constexpr int QPW     = QPB / 4;                      // 1024 quads per wave
constexpr int PER_THR = QPW / 64;                     // 16 quads per thread
static_assert((long long)NBLK * QPB == NQ, "exact cover");

constexpr int EDGE_ITEMS   = B_ * T_ + B_ * F_;       // 81,920
constexpr int EDGE_PER_BLK = EDGE_ITEMS / NBLK;       // 40
static_assert(EDGE_PER_BLK * NBLK == EDGE_ITEMS, "exact edge cover");

typedef float vf4 __attribute__((ext_vector_type(4)));
typedef int   vi4 __attribute__((ext_vector_type(4)));

// ---------------- block reduction helper ----------------
__device__ __forceinline__ void block_reduce(float& s, int& c) {
    #pragma unroll
    for (int off = 32; off > 0; off >>= 1) {
        s += __shfl_down(s, off, 64);
        c += __shfl_down(c, off, 64);
    }
    __shared__ float ss[4];
    __shared__ int   sc[4];
    int lane = threadIdx.x & 63, wave = threadIdx.x >> 6;
    if (lane == 0) { ss[wave] = s; sc[wave] = c; }
    __syncthreads();
    if (threadIdx.x == 0) {
        s = ss[0] + ss[1] + ss[2] + ss[3];
        c = sc[0] + sc[1] + sc[2] + sc[3];
    }
}

// ---------------- fused: streaming masked sum + edge corr + finalize -----
__global__ __launch_bounds__(256) void recall_fused(
    const float* __restrict__ pred,
    const int* __restrict__ gt,
    float* __restrict__ bsum,
    unsigned int* __restrict__ bcnt,
    unsigned int* __restrict__ ticket,
    float* __restrict__ out)
{
    const unsigned lane = threadIdx.x & 63;
    const unsigned wave = threadIdx.x >> 6;
    // Descending data mapping: block 0 reads the highest addresses (written
    // most recently by the harness restore/poison) first.
    const unsigned db = (unsigned)(NBLK - 1) - blockIdx.x;
    const size_t base = (size_t)db * QPB + (size_t)wave * QPW + lane;

    const vf4* p4 = (const vf4*)pred;
    const vi4* g4 = (const vi4*)gt;

    float s0 = 0.f, s1 = 0.f, s2 = 0.f, s3 = 0.f;
    int   c0 = 0, c1 = 0, c2 = 0, c3 = 0;

    // Fused edge-remap correction: 40 items per block, threads 0..39.
    //   item < B*T:          f==0 row (b,t): remap f->1, t->max(t,1)
    //   item >= B*T:         t==0 col, f>=1: remap t->1 (f==0,t==0 already
    //                        covered by the first range)
    // corr = p[adj] - p[raw] at gt-nonzero positions; count is unchanged.
    if (threadIdx.x < EDGE_PER_BLK) {
        unsigned idx = blockIdx.x * EDGE_PER_BLK + threadIdx.x;
        if (idx < (unsigned)(B_ * T_)) {
            unsigned b = idx >> 11, t = idx & (T_ - 1);
            unsigned raw = (b << 20) | t;
            unsigned tp  = (t == 0u) ? 1u : t;
            unsigned adj = (b << 20) | (1u << 11) | tp;
            if (gt[raw]) s0 += pred[adj] - pred[raw];
        } else {
            unsigned i2 = idx - (unsigned)(B_ * T_);
            unsigned b = i2 >> 9, f = i2 & (F_ - 1);
            if (f != 0u) {
                unsigned raw = (b << 20) | (f << 11);
                if (gt[raw]) s0 += pred[raw + 1] - pred[raw];
            }
        }
    }

    // Streaming masked sum over this block's contiguous 64KB/array chunk.
    // nt loads (proven faster than cached in R10's A/B) + 4-deep batching:
    // 8 independent dwordx4 loads issued before any consumption.
    #pragma unroll
    for (int k = 0; k < PER_THR; k += 4) {
        const size_t q0 = base + (size_t)(k + 0) * 64;
        const size_t q1 = base + (size_t)(k + 1) * 64;
        const size_t q2 = base + (size_t)(k + 2) * 64;
        const size_t q3 = base + (size_t)(k + 3) * 64;
        vf4 p0 = __builtin_nontemporal_load(&p4[q0]);
        vf4 p1 = __builtin_nontemporal_load(&p4[q1]);
        vf4 p2 = __builtin_nontemporal_load(&p4[q2]);
        vf4 p3 = __builtin_nontemporal_load(&p4[q3]);
        vi4 g0 = __builtin_nontemporal_load(&g4[q0]);
        vi4 g1 = __builtin_nontemporal_load(&g4[q1]);
        vi4 g2 = __builtin_nontemporal_load(&g4[q2]);
        vi4 g3 = __builtin_nontemporal_load(&g4[q3]);

        c0 += (g0.x != 0) + (g1.x != 0) + (g2.x != 0) + (g3.x != 0);
        c1 += (g0.y != 0) + (g1.y != 0) + (g2.y != 0) + (g3.y != 0);
        c2 += (g0.z != 0) + (g1.z != 0) + (g2.z != 0) + (g3.z != 0);
        c3 += (g0.w != 0) + (g1.w != 0) + (g2.w != 0) + (g3.w != 0);

        s0 += (g0.x ? p0.x : 0.f);
        s1 += (g0.y ? p0.y : 0.f);
        s2 += (g0.z ? p0.z : 0.f);
        s3 += (g0.w ? p0.w : 0.f);
        s0 += (g1.x ? p1.x : 0.f);
        s1 += (g1.y ? p1.y : 0.f);
        s2 += (g1.z ? p1.z : 0.f);
        s3 += (g1.w ? p1.w : 0.f);
        s0 += (g2.x ? p2.x : 0.f);
        s1 += (g2.y ? p2.y : 0.f);
        s2 += (g2.z ? p2.z : 0.f);
        s3 += (g2.w ? p2.w : 0.f);
        s0 += (g3.x ? p3.x : 0.f);
        s1 += (g3.y ? p3.y : 0.f);
        s2 += (g3.z ? p3.z : 0.f);
        s3 += (g3.w ? p3.w : 0.f);
    }

    float lsum = (s0 + s1) + (s2 + s3);
    int   lcnt = (c0 + c1) + (c2 + c3);

    block_reduce(lsum, lcnt);

    // Last-block ticket: release partials, take a ticket; winner finalizes.
    __shared__ bool last;
    if (threadIdx.x == 0) {
        bsum[blockIdx.x] = lsum;
        bcnt[blockIdx.x] = (unsigned int)lcnt;
        __threadfence();                      // release: flush to device scope
        unsigned t = atomicAdd(ticket, 1u);   // device-scope by default
        last = (t == (unsigned)(NBLK - 1));
    }
    __syncthreads();

    if (last) {
        __threadfence();                      // acquire: invalidate stale L2
        float s = 0.f;
        int   c = 0;
        for (int j = threadIdx.x; j < NBLK; j += BLK) {
            s += bsum[j];
            c += (int)bcnt[j];
        }
        block_reduce(s, c);
        if (threadIdx.x == 0) {
            out[0] = (c > 0) ? (s / (float)c) : 0.0f;
            *ticket = 0;                      // reset for next replay
        }
    }
}

extern "C" void kernel_launch(void* const* d_in, const int* in_sizes, int n_in,
                              void* d_out, int out_size, void* d_ws, size_t ws_size,
                              hipStream_t stream)
{
    const float* pred = (const float*)d_in[0];
    const int*   gt   = (const int*)d_in[1];
    float*       out  = (float*)d_out;

    float*        bsum   = (float*)d_ws;
    unsigned int* bcnt   = (unsigned int*)((char*)d_ws + NBLK * sizeof(float));
    unsigned int* ticket = (unsigned int*)((char*)d_ws + 2 * NBLK * sizeof(float));

    // Stream-ordered (graph-capturable) zero of the ticket word; the winner
    // also re-zeros it, so this is belt-and-suspenders for the first run.
    hipMemsetAsync(ticket, 0, sizeof(unsigned int), stream);

    recall_fused<<<NBLK, BLK, 0, stream>>>(pred, gt, bsum, bcnt, ticket, out);
}

// Round 5
// 256.992 us; speedup vs baseline: 1.3817x; 1.3817x over previous
//
#include <hip/hip_runtime.h>

// Recall over [B=32, F=512, T=2048]:
//   p_adj[b,f,t] = predicted[b, f==0?1:f, t==0?1:t]
//   out = sum(p_adj * (gt!=0)) / count(gt!=0), or 0 if count==0.
//
// R14: revert to R11's proven two-kernel structure (251.7 us). Both fusion
// attempts failed: R12 cooperative launch silently no-ops under graph
// capture; R13 ticket+__threadfence regressed main 2x (agent-scope fence
// = L2 writeback/invalidate x2048 blocks nukes the LLC-hit read stream —
// warm replays were traffic-invariant at 152 us, proving cache-path
// destruction, not BW). Steady-state model: ~231 us fixed harness traffic
// (3 x 512 MiB fill/restore ops at ~6.9 TB/s) + main ~18 us (256 MiB read
// from restore-warmed L3 at ~14 TB/s) + fin ~3 us.
// Only change vs R11: batch loads issued interleaved (p0,g0,p1,g1,...) so
// consuming pair i needs only vmcnt(6-2i), keeping later loads in flight
// through the consume phase (R11 issued all p then all g and consumed g0
// first, forcing a full drain).
// Structure: nt loads, 4-deep batches, descending block->data mapping,
// fused edge correction, 2048 blocks x 256 thr (8 blocks/CU, 32 waves/CU),
// block covers contiguous 64KB per array, single resident round.

constexpr int B_ = 32;
constexpr int F_ = 512;
constexpr int T_ = 2048;
constexpr long long NTOT = (long long)B_ * F_ * T_;   // 2^25
constexpr int NQ      = (int)(NTOT >> 2);             // 8,388,608 quads
constexpr int BLK     = 256;
constexpr int NBLK    = 2048;                         // 8 blocks/CU, 1 round
constexpr int QPB     = NQ / NBLK;                    // 4096 quads per block
constexpr int QPW     = QPB / 4;                      // 1024 quads per wave
constexpr int PER_THR = QPW / 64;                     // 16 quads per thread
static_assert((long long)NBLK * QPB == NQ, "exact cover");

constexpr int EDGE_ITEMS   = B_ * T_ + B_ * F_;       // 81,920
constexpr int EDGE_PER_BLK = EDGE_ITEMS / NBLK;       // 40
static_assert(EDGE_PER_BLK * NBLK == EDGE_ITEMS, "exact edge cover");

typedef float vf4 __attribute__((ext_vector_type(4)));
typedef int   vi4 __attribute__((ext_vector_type(4)));

// ---------------- block reduction helper ----------------
__device__ __forceinline__ void block_reduce(float& s, int& c) {
    #pragma unroll
    for (int off = 32; off > 0; off >>= 1) {
        s += __shfl_down(s, off, 64);
        c += __shfl_down(c, off, 64);
    }
    __shared__ float ss[4];
    __shared__ int   sc[4];
    int lane = threadIdx.x & 63, wave = threadIdx.x >> 6;
    if (lane == 0) { ss[wave] = s; sc[wave] = c; }
    __syncthreads();
    if (threadIdx.x == 0) {
        s = ss[0] + ss[1] + ss[2] + ss[3];
        c = sc[0] + sc[1] + sc[2] + sc[3];
    }
}

// ---------------- main: streaming masked sum + fused edge correction ------
__global__ __launch_bounds__(256) void recall_main(
    const float* __restrict__ pred,
    const int* __restrict__ gt,
    float* __restrict__ bsum,
    unsigned int* __restrict__ bcnt)
{
    const unsigned lane = threadIdx.x & 63;
    const unsigned wave = threadIdx.x >> 6;
    // Descending data mapping: block 0 reads the highest addresses (written
    // most recently by the harness restore/poison) first.
    const unsigned db = (unsigned)(NBLK - 1) - blockIdx.x;
    const size_t base = (size_t)db * QPB + (size_t)wave * QPW + lane;

    const vf4* p4 = (const vf4*)pred;
    const vi4* g4 = (const vi4*)gt;

    float s0 = 0.f, s1 = 0.f, s2 = 0.f, s3 = 0.f;
    int   c0 = 0, c1 = 0, c2 = 0, c3 = 0;

    // Fused edge-remap correction: 40 items per block, threads 0..39.
    //   item < B*T:          f==0 row (b,t): remap f->1, t->max(t,1)
    //   item >= B*T:         t==0 col, f>=1: remap t->1 (f==0,t==0 already
    //                        covered by the first range)
    // corr = p[adj] - p[raw] at gt-nonzero positions; count is unchanged.
    if (threadIdx.x < EDGE_PER_BLK) {
        unsigned idx = blockIdx.x * EDGE_PER_BLK + threadIdx.x;
        if (idx < (unsigned)(B_ * T_)) {
            unsigned b = idx >> 11, t = idx & (T_ - 1);
            unsigned raw = (b << 20) | t;
            unsigned tp  = (t == 0u) ? 1u : t;
            unsigned adj = (b << 20) | (1u << 11) | tp;
            if (gt[raw]) s0 += pred[adj] - pred[raw];
        } else {
            unsigned i2 = idx - (unsigned)(B_ * T_);
            unsigned b = i2 >> 9, f = i2 & (F_ - 1);
            if (f != 0u) {
                unsigned raw = (b << 20) | (f << 11);
                if (gt[raw]) s0 += pred[raw + 1] - pred[raw];
            }
        }
    }

    // Streaming masked sum over this block's contiguous 64KB/array chunk.
    // nt loads + 4-deep batching. Issue order interleaved (p,g per pair) so
    // consuming pair i only requires the first 2i+2 loads to have returned,
    // keeping the remaining loads in flight (finer vmcnt waits).
    #pragma unroll
    for (int k = 0; k < PER_THR; k += 4) {
        const size_t q0 = base + (size_t)(k + 0) * 64;
        const size_t q1 = base + (size_t)(k + 1) * 64;
        const size_t q2 = base + (size_t)(k + 2) * 64;
        const size_t q3 = base + (size_t)(k + 3) * 64;
        vf4 p0 = __builtin_nontemporal_load(&p4[q0]);
        vi4 g0 = __builtin_nontemporal_load(&g4[q0]);
        vf4 p1 = __builtin_nontemporal_load(&p4[q1]);
        vi4 g1 = __builtin_nontemporal_load(&g4[q1]);
        vf4 p2 = __builtin_nontemporal_load(&p4[q2]);
        vi4 g2 = __builtin_nontemporal_load(&g4[q2]);
        vf4 p3 = __builtin_nontemporal_load(&p4[q3]);
        vi4 g3 = __builtin_nontemporal_load(&g4[q3]);

        c0 += (g0.x != 0);
        c1 += (g0.y != 0);
        c2 += (g0.z != 0);
        c3 += (g0.w != 0);
        s0 += (g0.x ? p0.x : 0.f);
        s1 += (g0.y ? p0.y : 0.f);
        s2 += (g0.z ? p0.z : 0.f);
        s3 += (g0.w ? p0.w : 0.f);

        c0 += (g1.x != 0);
        c1 += (g1.y != 0);
        c2 += (g1.z != 0);
        c3 += (g1.w != 0);
        s0 += (g1.x ? p1.x : 0.f);
        s1 += (g1.y ? p1.y : 0.f);
        s2 += (g1.z ? p1.z : 0.f);
        s3 += (g1.w ? p1.w : 0.f);

        c0 += (g2.x != 0);
        c1 += (g2.y != 0);
        c2 += (g2.z != 0);
        c3 += (g2.w != 0);
        s0 += (g2.x ? p2.x : 0.f);
        s1 += (g2.y ? p2.y : 0.f);
        s2 += (g2.z ? p2.z : 0.f);
        s3 += (g2.w ? p2.w : 0.f);

        c0 += (g3.x != 0);
        c1 += (g3.y != 0);
        c2 += (g3.z != 0);
        c3 += (g3.w != 0);
        s0 += (g3.x ? p3.x : 0.f);
        s1 += (g3.y ? p3.y : 0.f);
        s2 += (g3.z ? p3.z : 0.f);
        s3 += (g3.w ? p3.w : 0.f);
    }

    float lsum = (s0 + s1) + (s2 + s3);
    int   lcnt = (c0 + c1) + (c2 + c3);

    block_reduce(lsum, lcnt);
    if (threadIdx.x == 0) {
        bsum[blockIdx.x] = lsum;
        bcnt[blockIdx.x] = (unsigned int)lcnt;
    }
}

// ---------------- finalize ----------------
__global__ __launch_bounds__(256) void recall_fin(
    const float* __restrict__ bsum,
    const unsigned int* __restrict__ bcnt,
    float* __restrict__ out)
{
    float s = 0.f;
    int   c = 0;
    for (int j = threadIdx.x; j < NBLK; j += BLK) {
        s += bsum[j];
        c += (int)bcnt[j];
    }
    block_reduce(s, c);
    if (threadIdx.x == 0)
        out[0] = (c > 0) ? (s / (float)c) : 0.0f;
}

extern "C" void kernel_launch(void* const* d_in, const int* in_sizes, int n_in,
                              void* d_out, int out_size, void* d_ws, size_t ws_size,
                              hipStream_t stream)
{
    const float* pred = (const float*)d_in[0];
    const int*   gt   = (const int*)d_in[1];
    float*       out  = (float*)d_out;

    float*        bsum = (float*)d_ws;
    unsigned int* bcnt = (unsigned int*)((char*)d_ws + NBLK * sizeof(float));

    recall_main<<<NBLK, BLK, 0, stream>>>(pred, gt, bsum, bcnt);
    recall_fin<<<1, BLK, 0, stream>>>(bsum, bcnt, out);
}